// Round 3
// baseline (48.415 us; speedup 1.0000x reference)
//
#include <hip/hip_runtime.h>
#include <cmath>

// RTMDet decode, fused, 4-way class-split for occupancy.
// Per spatial position: conf = sigmoid(max_c logit), class = argmax_c logit (first occurrence),
// box = clip([gx-l, gy-t, gx+r, gy+d], 0, 639), gx = w*step, gy = h*step.
// Output layout (flat float32 in d_out): boxes [64,8400,4] | scores [64,8400] | classes [64,8400].
//
// Grid: 2100 blocks x 256 threads (level boundaries on block boundaries):
//   [0,1600)    -> level 0 (80x80, step 8)
//   [1600,2000) -> level 1 (40x40, step 16)
//   [2000,2100) -> level 2 (20x20, step 32)
//
// cls argmax: each QUAD (4 consecutive positions) is handled by 4 lanes; lane chunk = tid&3
//   scans classes [20*chunk, 20*chunk+20) with float4 loads (4 positions at once), then two
//   __shfl_xor merges (^1, ^2) produce the full 80-class argmax in every lane of the group.
//   Lane then emits score/class for position (quad*4 + chunk) -> lane-contiguous stores.
// boxes: 1 position per thread, 4 coalesced scalar loads, 1 coalesced float4 store.

constexpr int B_   = 64;
constexpr int NC   = 80;
constexpr int NTOT = 8400;   // 6400 + 1600 + 400

__device__ __forceinline__ float sigmoidf_(float x) { return 1.0f / (1.0f + __expf(-x)); }

template<int HW, int W, int STEP, int NOFF>
__device__ __forceinline__ void decode_level(
    const float* __restrict__ cls, const float* __restrict__ box,
    float* __restrict__ oboxes, float* __restrict__ oscores, float* __restrict__ oclasses,
    int lbid, int tid)
{
    constexpr int QPI = HW / 4;                 // quads per image

    // ---------- class max/argmax: 4 lanes per quad, 20 classes per lane ----------
    int gt    = lbid * 256 + tid;               // global quad-thread index
    int quad  = gt >> 2;                        // level-local quad, in [0, 64*QPI)
    int chunk = gt & 3;                         // class chunk 0..3
    int b     = quad / QPI;                     // compile-time QPI -> magic mul
    int p     = (quad - b * QPI) << 2;          // first of 4 consecutive positions

    const float* cbase = cls + (size_t)b * NC * HW + (size_t)(chunk * 20) * HW + p;
    float m[4]  = {-3.4e38f, -3.4e38f, -3.4e38f, -3.4e38f};
    int   ci[4] = {0, 0, 0, 0};
    #pragma unroll
    for (int c = 0; c < 20; ++c) {
        float4 v = *reinterpret_cast<const float4*>(cbase + (size_t)c * HW);
        float vv[4] = {v.x, v.y, v.z, v.w};
        #pragma unroll
        for (int j = 0; j < 4; ++j) {
            if (vv[j] > m[j]) { m[j] = vv[j]; ci[j] = c; }   // strict > : first occurrence
        }
    }
    int cofs = chunk * 20;
    #pragma unroll
    for (int j = 0; j < 4; ++j) ci[j] += cofs;  // globalize class index

    // merge across the 4 chunk lanes (^1 then ^2); lower class index wins ties
    #pragma unroll
    for (int mask = 1; mask <= 2; mask <<= 1) {
        #pragma unroll
        for (int j = 0; j < 4; ++j) {
            float om = __shfl_xor(m[j],  mask);
            int   oc = __shfl_xor(ci[j], mask);
            if (om > m[j] || (om == m[j] && oc < ci[j])) { m[j] = om; ci[j] = oc; }
        }
    }

    // lane writes its own position (quad*4 + chunk) -> fully coalesced scalar stores
    size_t obase = (size_t)b * NTOT + NOFF + p + chunk;
    oscores [obase] = sigmoidf_(m[chunk]);
    oclasses[obase] = (float)ci[chunk];

    // ---------- boxes: 1 lane-contiguous position per thread ----------
    {
        int P  = lbid * 256 + tid;              // level-local element pos in [0, 64*HW)
        int bb = P / HW;                        // compile-time HW -> magic mul
        int pp = P - bb * HW;
        int hh = pp / W;                        // compile-time W -> magic mul
        int ww = pp - hh * W;

        const float* bbase = box + (size_t)bb * 4 * HW + pp;
        float l  = bbase[0];                    // lanes at consecutive pp -> coalesced
        float tt = bbase[HW];
        float r  = bbase[2 * HW];
        float dd = bbase[3 * HW];

        float gx = (float)(ww * STEP);
        float gy = (float)(hh * STEP);
        float4 o;
        o.x = fminf(fmaxf(gx - l,  0.0f), 639.0f);
        o.y = fminf(fmaxf(gy - tt, 0.0f), 639.0f);
        o.z = fminf(fmaxf(gx + r,  0.0f), 639.0f);
        o.w = fminf(fmaxf(gy + dd, 0.0f), 639.0f);

        size_t ob = (size_t)bb * NTOT + NOFF + pp;
        *reinterpret_cast<float4*>(oboxes + ob * 4) = o;    // lanes contiguous -> coalesced
    }
}

__global__ __launch_bounds__(256) void rtmdet_decode_fused(
    const float* __restrict__ cls0, const float* __restrict__ box0,
    const float* __restrict__ cls1, const float* __restrict__ box1,
    const float* __restrict__ cls2, const float* __restrict__ box2,
    float* __restrict__ oboxes, float* __restrict__ oscores, float* __restrict__ oclasses)
{
    int bid = blockIdx.x;
    int tid = threadIdx.x;
    if (bid < 1600) {
        decode_level<6400, 80,  8,    0>(cls0, box0, oboxes, oscores, oclasses, bid,        tid);
    } else if (bid < 2000) {
        decode_level<1600, 40, 16, 6400>(cls1, box1, oboxes, oscores, oclasses, bid - 1600, tid);
    } else {
        decode_level< 400, 20, 32, 8000>(cls2, box2, oboxes, oscores, oclasses, bid - 2000, tid);
    }
}

extern "C" void kernel_launch(void* const* d_in, const int* in_sizes, int n_in,
                              void* d_out, int out_size, void* d_ws, size_t ws_size,
                              hipStream_t stream) {
    const float* cls0 = (const float*)d_in[0];
    const float* box0 = (const float*)d_in[1];
    const float* cls1 = (const float*)d_in[2];
    const float* box1 = (const float*)d_in[3];
    const float* cls2 = (const float*)d_in[4];
    const float* box2 = (const float*)d_in[5];

    float* oboxes   = (float*)d_out;
    float* oscores  = oboxes  + (size_t)B_ * NTOT * 4;
    float* oclasses = oscores + (size_t)B_ * NTOT;

    rtmdet_decode_fused<<<2100, 256, 0, stream>>>(cls0, box0, cls1, box1, cls2, box2,
                                                  oboxes, oscores, oclasses);
}

// Round 4
// 33.564 us; speedup vs baseline: 1.4425x; 1.4425x over previous
//
#include <hip/hip_runtime.h>
#include <cmath>

// RTMDet decode, fused, 2-positions-per-thread (float2) for occupancy.
// Per spatial position: conf = sigmoid(max_c logit), class = argmax_c logit (first occurrence),
// box = clip([gx-l, gy-t, gx+r, gy+d], 0, 639), gx = w*step, gy = h*step.
// Output layout (flat float32 in d_out): boxes [64,8400,4] | scores [64,8400] | classes [64,8400].
//
// Grid: 1050 blocks x 256 threads (level boundaries on block boundaries):
//   [0,800)     -> level 0 (80x80, step 8)
//   [800,1000)  -> level 1 (40x40, step 16)
//   [1000,1050) -> level 2 (20x20, step 32)
//
// R3 lesson: cross-lane argmax merge (__shfl_xor) lowered via LDS with 1.3M bank conflicts and
// regressed. Here each thread owns the full 80-class scan (no cross-lane traffic, no LDS);
// occupancy is raised by halving the spatial tile: 2 consecutive positions/thread via float2
// loads (512 B per wave-instruction, perfectly coalesced). Box loads hoisted for extra MLP.

constexpr int B_   = 64;
constexpr int NC   = 80;
constexpr int NTOT = 8400;   // 6400 + 1600 + 400

__device__ __forceinline__ float sigmoidf_(float x) { return 1.0f / (1.0f + __expf(-x)); }

template<int HW, int W, int STEP, int NOFF>
__device__ __forceinline__ void decode_level(
    const float* __restrict__ cls, const float* __restrict__ box,
    float* __restrict__ oboxes, float* __restrict__ oscores, float* __restrict__ oclasses,
    int lbid, int tid)
{
    constexpr int PPI = HW / 2;                 // pairs per image

    int t = lbid * 256 + tid;                   // pair index in [0, 64*PPI)
    int b = t / PPI;                            // compile-time PPI -> magic mul
    int p = (t - b * PPI) << 1;                 // first of 2 consecutive positions
    int h = p / W;                              // compile-time W -> magic mul
    int w = p - h * W;

    // ---------- hoisted box loads (independent of class loop -> early MLP) ----------
    const float* bbase = box + (size_t)b * 4 * HW + p;
    float2 bl = *reinterpret_cast<const float2*>(bbase);            // l for p, p+1
    float2 bt = *reinterpret_cast<const float2*>(bbase + HW);       // t
    float2 br = *reinterpret_cast<const float2*>(bbase + 2 * HW);   // r
    float2 bd = *reinterpret_cast<const float2*>(bbase + 3 * HW);   // d

    // ---------- class max/argmax: full 80-class scan per thread, float2 loads ----------
    const float* cbase = cls + (size_t)b * NC * HW + p;
    float m[2]  = {-3.4e38f, -3.4e38f};
    int   ci[2] = {0, 0};
    #pragma unroll 16
    for (int c = 0; c < NC; ++c) {
        float2 v = *reinterpret_cast<const float2*>(cbase + (size_t)c * HW);
        if (v.x > m[0]) { m[0] = v.x; ci[0] = c; }   // strict > : first occurrence
        if (v.y > m[1]) { m[1] = v.y; ci[1] = c; }
    }

    // ---------- stores (all lane-contiguous) ----------
    size_t obase = (size_t)b * NTOT + NOFF + p;
    *reinterpret_cast<float2*>(oscores  + obase) = make_float2(sigmoidf_(m[0]), sigmoidf_(m[1]));
    *reinterpret_cast<float2*>(oclasses + obase) = make_float2((float)ci[0], (float)ci[1]);

    float gy = (float)(h * STEP);
    #pragma unroll
    for (int j = 0; j < 2; ++j) {
        float gx = (float)((w + j) * STEP);
        float l  = j ? bl.y : bl.x;
        float tt = j ? bt.y : bt.x;
        float r  = j ? br.y : br.x;
        float dd = j ? bd.y : bd.x;
        float4 o;
        o.x = fminf(fmaxf(gx - l,  0.0f), 639.0f);
        o.y = fminf(fmaxf(gy - tt, 0.0f), 639.0f);
        o.z = fminf(fmaxf(gx + r,  0.0f), 639.0f);
        o.w = fminf(fmaxf(gy + dd, 0.0f), 639.0f);
        *reinterpret_cast<float4*>(oboxes + (obase + j) * 4) = o;   // coalesced float4
    }
}

__global__ __launch_bounds__(256) void rtmdet_decode_fused(
    const float* __restrict__ cls0, const float* __restrict__ box0,
    const float* __restrict__ cls1, const float* __restrict__ box1,
    const float* __restrict__ cls2, const float* __restrict__ box2,
    float* __restrict__ oboxes, float* __restrict__ oscores, float* __restrict__ oclasses)
{
    int bid = blockIdx.x;
    int tid = threadIdx.x;
    if (bid < 800) {
        decode_level<6400, 80,  8,    0>(cls0, box0, oboxes, oscores, oclasses, bid,        tid);
    } else if (bid < 1000) {
        decode_level<1600, 40, 16, 6400>(cls1, box1, oboxes, oscores, oclasses, bid - 800,  tid);
    } else {
        decode_level< 400, 20, 32, 8000>(cls2, box2, oboxes, oscores, oclasses, bid - 1000, tid);
    }
}

extern "C" void kernel_launch(void* const* d_in, const int* in_sizes, int n_in,
                              void* d_out, int out_size, void* d_ws, size_t ws_size,
                              hipStream_t stream) {
    const float* cls0 = (const float*)d_in[0];
    const float* box0 = (const float*)d_in[1];
    const float* cls1 = (const float*)d_in[2];
    const float* box1 = (const float*)d_in[3];
    const float* cls2 = (const float*)d_in[4];
    const float* box2 = (const float*)d_in[5];

    float* oboxes   = (float*)d_out;
    float* oscores  = oboxes  + (size_t)B_ * NTOT * 4;
    float* oclasses = oscores + (size_t)B_ * NTOT;

    rtmdet_decode_fused<<<1050, 256, 0, stream>>>(cls0, box0, cls1, box1, cls2, box2,
                                                  oboxes, oscores, oclasses);
}